// Round 1
// baseline (1474.875 us; speedup 1.0000x reference)
//
#include <hip/hip_runtime.h>
#include <hip/hip_bf16.h>

#define M_TOK 8192
#define K_IN  4096
#define N_OUT 11008

typedef __bf16 bf16x8 __attribute__((ext_vector_type(8)));
typedef float  f32x4  __attribute__((ext_vector_type(4)));

__device__ __forceinline__ unsigned short f2bf_rne(float f) {
  unsigned int u = __float_as_uint(f);
  u += 0x7FFFu + ((u >> 16) & 1u);   // round-to-nearest-even
  return (unsigned short)(u >> 16);
}

// ---- conversion kernels (memory-bound) ----
__global__ void cvt_f32_to_bf16(const float4* __restrict__ in,
                                ushort4* __restrict__ out, int n4) {
  int i = blockIdx.x * blockDim.x + threadIdx.x;
  if (i >= n4) return;
  float4 v = in[i];
  ushort4 o;
  o.x = f2bf_rne(v.x); o.y = f2bf_rne(v.y);
  o.z = f2bf_rne(v.z); o.w = f2bf_rne(v.w);
  out[i] = o;
}

__global__ void cvt_i32_to_bf16(const int4* __restrict__ in,
                                ushort4* __restrict__ out, int n4) {
  int i = blockIdx.x * blockDim.x + threadIdx.x;
  if (i >= n4) return;
  int4 v = in[i];
  ushort4 o;  // values {0,1,2} -> exact in bf16
  o.x = f2bf_rne((float)v.x); o.y = f2bf_rne((float)v.y);
  o.z = f2bf_rne((float)v.z); o.w = f2bf_rne((float)v.w);
  out[i] = o;
}

// ---- bf16 NT GEMM, 128x128 tile, BK=32, m97-style global_load_lds staging ----
// C[t][o] = sum_k A[t][k]*B[o][k], epilogue *scale[o]+bias[o]
__global__ __launch_bounds__(256) void gemm_bf16_bt(
    const __bf16* __restrict__ A,   // [M][K]
    const __bf16* __restrict__ B,   // [N][K]  (row-major over out-features)
    const float* __restrict__ scale,
    const float* __restrict__ bias,
    float* __restrict__ C)          // [M][N]
{
  __shared__ __align__(16) __bf16 As[128 * 32];
  __shared__ __align__(16) __bf16 Bs[128 * 32];

  const int tid  = threadIdx.x;
  const int lane = tid & 63;
  const int wave = tid >> 6;
  const long long bm = (long long)blockIdx.y * 128;
  const long long bn = (long long)blockIdx.x * 128;

  const int wm = (wave >> 1) * 64;   // wave sub-tile origin in M
  const int wn = (wave & 1) * 64;    // and in N
  const int lr = lane & 15;          // A-operand m / B-operand n
  const int lk = (lane >> 4) * 8;    // k offset within BK for the frag

  // staging map: thread t owns the 16B at LDS flat byte offset t*16
  // (wave-uniform base + lane*16 as required by global_load_lds)
  const int srow = tid >> 2;         // 0..63 (row stride = 32 bf16 = 64B)
  const int scol = (tid & 3) * 8;    // bf16 element offset within row

  const __bf16* a0 = A + (bm + srow) * K_IN + scol;
  const __bf16* a1 = A + (bm + srow + 64) * K_IN + scol;
  const __bf16* b0 = B + (bn + srow) * K_IN + scol;
  const __bf16* b1 = B + (bn + srow + 64) * K_IN + scol;

  f32x4 acc[4][4] = {};

  for (int k0 = 0; k0 < K_IN; k0 += 32) {
    __builtin_amdgcn_global_load_lds(
        (const __attribute__((address_space(1))) void*)(a0 + k0),
        (__attribute__((address_space(3))) void*)(As + tid * 8), 16, 0, 0);
    __builtin_amdgcn_global_load_lds(
        (const __attribute__((address_space(1))) void*)(a1 + k0),
        (__attribute__((address_space(3))) void*)(As + 2048 + tid * 8), 16, 0, 0);
    __builtin_amdgcn_global_load_lds(
        (const __attribute__((address_space(1))) void*)(b0 + k0),
        (__attribute__((address_space(3))) void*)(Bs + tid * 8), 16, 0, 0);
    __builtin_amdgcn_global_load_lds(
        (const __attribute__((address_space(1))) void*)(b1 + k0),
        (__attribute__((address_space(3))) void*)(Bs + 2048 + tid * 8), 16, 0, 0);
    __syncthreads();

    bf16x8 af[4], bfv[4];
#pragma unroll
    for (int i = 0; i < 4; ++i)
      af[i] = *(const bf16x8*)(As + (wm + i * 16 + lr) * 32 + lk);
#pragma unroll
    for (int j = 0; j < 4; ++j)
      bfv[j] = *(const bf16x8*)(Bs + (wn + j * 16 + lr) * 32 + lk);

#pragma unroll
    for (int i = 0; i < 4; ++i)
#pragma unroll
      for (int j = 0; j < 4; ++j)
        acc[i][j] = __builtin_amdgcn_mfma_f32_16x16x32_bf16(
            af[i], bfv[j], acc[i][j], 0, 0, 0);
    __syncthreads();
  }

  // epilogue: C/D layout col=lane&15, row=(lane>>4)*4+reg  [m89-verified]
  const int quad = lane >> 4;
#pragma unroll
  for (int j = 0; j < 4; ++j) {
    const long long col = bn + wn + j * 16 + lr;
    const float s  = scale[col];
    const float bb = bias[col];
#pragma unroll
    for (int i = 0; i < 4; ++i) {
      const long long row0 = bm + wm + i * 16 + quad * 4;
#pragma unroll
      for (int r = 0; r < 4; ++r)
        C[(row0 + r) * N_OUT + col] = acc[i][j][r] * s + bb;
    }
  }
}

// ---- safety-net fallback if ws_size is too small (slow but correct) ----
__global__ void naive_qlinear(const float* __restrict__ in,
                              const int* __restrict__ w,
                              const float* __restrict__ scale,
                              const float* __restrict__ bias,
                              float* __restrict__ out) {
  long long total = (long long)M_TOK * N_OUT;
  for (long long idx = (long long)blockIdx.x * blockDim.x + threadIdx.x;
       idx < total; idx += (long long)gridDim.x * blockDim.x) {
    int t = (int)(idx / N_OUT), o = (int)(idx % N_OUT);
    const float* ip = in + (long long)t * K_IN;
    const int*   wp = w  + (long long)o * K_IN;
    float acc = 0.f;
    for (int k = 0; k < K_IN; ++k) acc += ip[k] * (float)wp[k];
    out[idx] = acc * scale[o] + bias[o];
  }
}

extern "C" void kernel_launch(void* const* d_in, const int* in_sizes, int n_in,
                              void* d_out, int out_size, void* d_ws, size_t ws_size,
                              hipStream_t stream) {
  const float* input  = (const float*)d_in[0];
  const int*   qw     = (const int*)d_in[1];
  const float* wscale = (const float*)d_in[2];
  const float* wbias  = (const float*)d_in[3];
  float* out = (float*)d_out;

  const size_t a_elems = (size_t)M_TOK * K_IN;   // 33,554,432
  const size_t b_elems = (size_t)N_OUT * K_IN;   // 45,088,768
  const size_t need = (a_elems + b_elems) * sizeof(unsigned short); // ~157 MB

  if (ws_size < need) {
    naive_qlinear<<<8192, 256, 0, stream>>>(input, qw, wscale, wbias, out);
    return;
  }

  unsigned short* Abf = (unsigned short*)d_ws;
  unsigned short* Bbf = Abf + a_elems;

  const int na4 = (int)(a_elems / 4);
  const int nb4 = (int)(b_elems / 4);
  cvt_f32_to_bf16<<<(na4 + 255) / 256, 256, 0, stream>>>(
      (const float4*)input, (ushort4*)Abf, na4);
  cvt_i32_to_bf16<<<(nb4 + 255) / 256, 256, 0, stream>>>(
      (const int4*)qw, (ushort4*)Bbf, nb4);

  gemm_bf16_bt<<<dim3(N_OUT / 128, M_TOK / 128), 256, 0, stream>>>(
      (const __bf16*)Abf, (const __bf16*)Bbf, wscale, wbias, out);
}